// Round 5
// baseline (195.673 us; speedup 1.0000x reference)
//
#include <hip/hip_runtime.h>
#include <math.h>

// Problem constants
constexpr int S_    = 4096;
constexpr int Dm    = 896;
constexpr int NHd   = 14;
constexpr int NKVh  = 2;
constexpr int HDim  = 64;
constexpr int NQ    = NHd * HDim;        // 896
constexpr int NK    = NKVh * HDim;       // 128
constexpr int NQK   = NQ + NK;           // 1024 (qk buffer row stride)
constexpr int GROUPS = NHd / NKVh;       // 7
constexpr float L2B   = 19.9315685693241740873f;  // log2(1e6)
constexpr float LOG2E = 1.44269504088896340736f;

typedef __attribute__((ext_vector_type(8))) short bf16x8;
typedef __attribute__((ext_vector_type(4))) short bf16x4;
typedef __attribute__((ext_vector_type(4))) float f32x4;
typedef __attribute__((ext_vector_type(2))) int   i32x2;

__device__ __forceinline__ short f2bf(float f) {   // RNE float->bf16
  unsigned u = __builtin_bit_cast(unsigned, f);
  unsigned r = (u + 0x7FFFu + ((u >> 16) & 1u)) >> 16;
  return (short)r;
}

__device__ __forceinline__ int cvtpk(float lo, float hi) {  // 2xf32 -> packed bf16
  int r;
  asm("v_cvt_pk_bf16_f32 %0, %1, %2" : "=v"(r) : "v"(lo), "v"(hi));
  return r;
}

// async global->LDS, 16 bytes per lane; lds dest must be wave-uniform (HW adds lane*16)
__device__ __forceinline__ void gload16(const void* g, void* l) {
  __builtin_amdgcn_global_load_lds(
      (const __attribute__((address_space(1))) unsigned int*)g,
      (__attribute__((address_space(3))) unsigned int*)l, 16, 0, 0);
}

// ---------------------------------------------------------------------------
// Prep A: cvt hidden_states f32->bf16 (blocks 0..1791) + RoPE tables (1792..2303)
// ---------------------------------------------------------------------------
__global__ __launch_bounds__(256) void prep_small(
    const float* __restrict__ hs, short* __restrict__ hsb,
    float* __restrict__ cost, float* __restrict__ sint)
{
  int bid = blockIdx.x;
  if (bid < 1792) {
    int idx = bid * 256 + threadIdx.x;
    float4 a = ((const float4*)hs)[idx * 2];
    float4 b = ((const float4*)hs)[idx * 2 + 1];
    bf16x8 o;
    o[0] = f2bf(a.x); o[1] = f2bf(a.y); o[2] = f2bf(a.z); o[3] = f2bf(a.w);
    o[4] = f2bf(b.x); o[5] = f2bf(b.y); o[6] = f2bf(b.z); o[7] = f2bf(b.w);
    ((bf16x8*)hsb)[idx] = o;
  } else {
    int idx = (bid - 1792) * 256 + threadIdx.x;   // m*32 + j
    int m = idx >> 5, j = idx & 31;
    float invf = exp2f(-(float)j * (L2B / 32.0f));
    float th = (float)m * invf;
    float s, c;
    sincosf(th, &s, &c);
    cost[idx] = c;
    sint[idx] = s;
  }
}

// ---------------------------------------------------------------------------
// Prep B: transpose all weights f32 -> bf16.  grid (14, 32):
//   y<14: Wq -> wtq rows 0..895 ; y=14,15: Wk -> rows 896..1023 ;
//   y=16,17: Wv -> rows 1024..1151 ; y>=18: Wo -> wto.
// ---------------------------------------------------------------------------
__global__ __launch_bounds__(256) void transpose_all(
    const float* __restrict__ Wq, const float* __restrict__ Wk,
    const float* __restrict__ Wv, const float* __restrict__ Wo,
    short* __restrict__ wtq, short* __restrict__ wto)
{
  __shared__ float t[64 * 68];
  const int kt = blockIdx.x;
  const int by = blockIdx.y;
  const int tid = threadIdx.x;

  const float* src; int srcN, nt; short* dst; int rowOff;
  if (by < 14)      { src = Wq; srcN = NQ; nt = by;      dst = wtq; rowOff = 0; }
  else if (by < 16) { src = Wk; srcN = NK; nt = by - 14; dst = wtq; rowOff = 896; }
  else if (by < 18) { src = Wv; srcN = NK; nt = by - 16; dst = wtq; rowOff = 1024; }
  else              { src = Wo; srcN = NQ; nt = by - 18; dst = wto; rowOff = 0; }

  #pragma unroll
  for (int i = 0; i < 4; i++) {
    int idx = tid + i * 256;
    int r = idx >> 4, c4 = (idx & 15) * 4;
    *(float4*)&t[r * 68 + c4] =
        *(const float4*)&src[(size_t)(kt * 64 + r) * srcN + nt * 64 + c4];
  }
  __syncthreads();
  const int nl = tid >> 2;
  const int kc = (tid & 3) * 16;
  bf16x8 o0, o1;
  #pragma unroll
  for (int i = 0; i < 8; i++) o0[i] = f2bf(t[(kc + i) * 68 + nl]);
  #pragma unroll
  for (int i = 0; i < 8; i++) o1[i] = f2bf(t[(kc + 8 + i) * 68 + nl]);
  short* dp = dst + (size_t)(rowOff + nt * 64 + nl) * 896 + kt * 64 + kc;
  *(bf16x8*)dp = o0;
  *(bf16x8*)(dp + 8) = o1;
}

// ---------------------------------------------------------------------------
// MFMA GEMM, 128x128 tile, BK=64, 4 waves (2x2), m97 structure.
// EPI==0: QKV epilogue (bias + RoPE; Q scaled by log2e/8 for exp2 softmax;
//         writes qkb bf16 and vtb bf16 transposed)
// EPI==1: plain f32 store
// ---------------------------------------------------------------------------
template<int EPI>
__global__ __launch_bounds__(256) void gemm128(
    const short* __restrict__ A, const short* __restrict__ Bt,
    const float* __restrict__ biasq, const float* __restrict__ biask,
    const float* __restrict__ biasv,
    const float* __restrict__ cost, const float* __restrict__ sint,
    short* __restrict__ qkb, short* __restrict__ vtb,
    float* __restrict__ outp)
{
  __shared__ short Als[128 * 64];
  __shared__ short Bls[128 * 64];
  const int tid = threadIdx.x;
  const int lane = tid & 63;
  const int w = tid >> 6;
  const int wm = w >> 1, wn = w & 1;
  const int r16 = lane & 15, rg = lane >> 4;
  const int bm = blockIdx.x, bn = blockIdx.y;

  const f32x4 zero4 = {0.f, 0.f, 0.f, 0.f};
  f32x4 acc[4][4];
  #pragma unroll
  for (int mt = 0; mt < 4; mt++)
    #pragma unroll
    for (int nt = 0; nt < 4; nt++) acc[mt][nt] = zero4;

  const int srow = (lane >> 3);
  const int scol = (lane & 7) * 8;

  for (int kt = 0; kt < 14; ++kt) {
    __syncthreads();
    #pragma unroll
    for (int i = 0; i < 4; i++) {
      int c = i * 4 + w;
      int row = c * 8 + srow;
      gload16(A  + (size_t)(bm * 128 + row) * 896 + kt * 64 + scol, &Als[c * 512]);
      gload16(Bt + (size_t)(bn * 128 + row) * 896 + kt * 64 + scol, &Bls[c * 512]);
    }
    __syncthreads();

    bf16x8 af[4][2], bfr[4][2];
    #pragma unroll
    for (int mt = 0; mt < 4; mt++)
      #pragma unroll
      for (int ks = 0; ks < 2; ks++)
        af[mt][ks] = *(const bf16x8*)&Als[(wm * 64 + mt * 16 + r16) * 64 + ks * 32 + rg * 8];
    #pragma unroll
    for (int nt = 0; nt < 4; nt++)
      #pragma unroll
      for (int ks = 0; ks < 2; ks++)
        bfr[nt][ks] = *(const bf16x8*)&Bls[(wn * 64 + nt * 16 + r16) * 64 + ks * 32 + rg * 8];
    #pragma unroll
    for (int mt = 0; mt < 4; mt++)
      #pragma unroll
      for (int nt = 0; nt < 4; nt++)
        #pragma unroll
        for (int ks = 0; ks < 2; ks++)
          acc[mt][nt] = __builtin_amdgcn_mfma_f32_16x16x32_bf16(
              af[mt][ks], bfr[nt][ks], acc[mt][nt], 0, 0, 0);
  }

  if (EPI == 0) {
    const int nbase = bn * 128 + wn * 64;
    if (bn < 8) {
      // q (scaled by log2e/8) or k, with bias + RoPE
      const float scl = (bn < 7) ? (0.125f * LOG2E) : 1.0f;
      const float* bias = (bn < 7) ? biasq : (biask - 896);
      #pragma unroll
      for (int mt = 0; mt < 4; mt++) {
        const int m0 = bm * 128 + wm * 64 + mt * 16 + rg * 4;
        #pragma unroll
        for (int nt = 0; nt < 4; nt++) {
          int n = nbase + nt * 16 + r16;
          int j = n & 31;
          float sgn = (n & 32) ? 1.f : -1.f;
          float b0 = bias[n], b1 = bias[n ^ 32];
          #pragma unroll
          for (int r = 0; r < 4; r++) {
            int m = m0 + r;
            float c_ = cost[m * 32 + j], s_ = sint[m * 32 + j];
            float val = ((acc[mt][nt][r] + b0) * c_ +
                         sgn * (acc[mt][nt ^ 2][r] + b1) * s_) * scl;
            qkb[(size_t)m * NQK + n] = f2bf(val);
          }
        }
      }
    } else {
      // v -> vtb [128][4096] transposed
      #pragma unroll
      for (int mt = 0; mt < 4; mt++) {
        const int m0 = bm * 128 + wm * 64 + mt * 16 + rg * 4;
        #pragma unroll
        for (int nt = 0; nt < 4; nt++) {
          int vc = wn * 64 + nt * 16 + r16;
          float b0 = biasv[vc];
          bf16x4 pk;
          #pragma unroll
          for (int r = 0; r < 4; r++) pk[r] = f2bf(acc[mt][nt][r] + b0);
          *(bf16x4*)&vtb[(size_t)vc * S_ + m0] = pk;
        }
      }
    }
  } else {
    #pragma unroll
    for (int mt = 0; mt < 4; mt++) {
      const int m0 = bm * 128 + wm * 64 + mt * 16 + rg * 4;
      #pragma unroll
      for (int nt = 0; nt < 4; nt++) {
        int n = bn * 128 + wn * 64 + nt * 16 + r16;
        #pragma unroll
        for (int r = 0; r < 4; r++)
          outp[(size_t)(m0 + r) * NQ + n] = acc[mt][nt][r];
      }
    }
  }
}

// ---------------------------------------------------------------------------
// Flash attention v4: swapped QK^T (q = lane&15), QBLK=128, KBLK=64,
// 4 waves x 32 q-rows, no key-split (no merge). K/V staged via
// global_load_lds with pre-swizzled global source (linear LDS dest).
// In-register softmax: in-lane fmax tree + xor16/xor32 shuffles; defer-max
// (THR=8, exp2 domain); P packed via v_cvt_pk_bf16_f32 + 4 ds_write_b64/mt;
// row-sum l via ones-A MFMA. Grid (32,14) big-first; 4 blocks/CU.
// ---------------------------------------------------------------------------
__global__ __launch_bounds__(256, 4) void flash_mfma(
    const short* __restrict__ qkb, const short* __restrict__ vtb,
    short* __restrict__ attnb)
{
  __shared__ __align__(16) char lds[34816];   // K 8K | V 8K | P 4 waves x 4608
  char* KsB = lds;             // [64 key][64 hd] bf16, chunk^=(key&7)
  char* VtB = lds + 8192;      // [64 hd][64 key] bf16, chunk^=(hd&7)

  const int tid  = threadIdx.x;
  const int lane = tid & 63;
  const int w    = tid >> 6;          // m-group: rows w*32
  const int r16  = lane & 15;         // q within 16-tile
  const int rg   = lane >> 4;
  const int h    = blockIdx.y;
  const int kv   = h / GROUPS;
  const int qt   = 31 - (int)blockIdx.x;   // big tiles first
  const int q0   = qt * 128;
  char* Pw = lds + 16384 + w * 4608;  // per-wave P: [2 mt][16 q][144 B]
  const int kbase2 = (NQ + kv * HDim) * 2;

  // staging sources (pre-swizzled global chunk so LDS stays linear)
  const char* qkbB = (const char*)qkb;
  const char* vtbB = (const char*)vtb;
  const int c8   = tid & 7;
  const int key0 = tid >> 3;          // 0..31
  const int key1 = key0 + 32;
  const char* ksrc0 = qkbB + (size_t)key0 * 2048 + kbase2 + ((c8 ^ (key0 & 7)) << 4);
  const char* ksrc1 = qkbB + (size_t)key1 * 2048 + kbase2 + ((c8 ^ (key1 & 7)) << 4);
  const char* vsrc0 = vtbB + (size_t)(kv * 64 + key0) * 8192 + ((c8 ^ (key0 & 7)) << 4);
  const char* vsrc1 = vtbB + (size_t)(kv * 64 + key1) * 8192 + ((c8 ^ (key1 & 7)) << 4);
  char* kdst0 = KsB + w * 1024;       // + lane*16 by HW
  char* kdst1 = KsB + 4096 + w * 1024;
  char* vdst0 = VtB + w * 1024;
  char* vdst1 = VtB + 4096 + w * 1024;

  // Q fragments (already scaled by log2e/8): B-operand, col = q = r16
  bf16x8 aq[2][2];
  #pragma unroll
  for (int mt = 0; mt < 2; ++mt) {
    const short* qp = qkb + (size_t)(q0 + w * 32 + mt * 16 + r16) * NQK + h * HDim + rg * 8;
    aq[mt][0] = *(const bf16x8*)qp;
    aq[mt][1] = *(const bf16x8*)(qp + 32);
  }

  const f32x4 zero4 = {0.f, 0.f, 0.f, 0.f};
  f32x4 acc_o[2][4];                 // D[d][q]: d-tile nt', col q = r16
  f32x4 acc_l[2];                    // rowsum via ones-MFMA (use [0])
  float mrow[2] = {0.f, 0.f};        // running max (exp2 domain), per-lane q
  #pragma unroll
  for (int mt = 0; mt < 2; mt++) {
    acc_l[mt] = zero4;
    #pragma unroll
    for (int nt = 0; nt < 4; nt++) acc_o[mt][nt] = zero4;
  }

  bf16x8 ones;
  #pragma unroll
  for (int j = 0; j < 8; j++) ones[j] = (short)0x3F80;  // bf16(1.0)

  const int nkt = 2 * qt + 2;
  for (int kt = 0; kt < nkt; ++kt) {
    __syncthreads();                 // previous tile fully consumed
    gload16(ksrc0, kdst0);
    gload16(ksrc1, kdst1);
    gload16(vsrc0, vdst0);
    gload16(vsrc1, vdst1);
    ksrc0 += 131072; ksrc1 += 131072;   // 64 rows * 2048 B
    vsrc0 += 128;    vsrc1 += 128;      // 64 keys * 2 B
    __syncthreads();                 // vmcnt drained by compiler before barrier

    // S^T = K Q^T : sc[mt][nt] -> D[key = nt*16 + rg*4 + r][q = r16]
    f32x4 sc[2][4];
    #pragma unroll
    for (int mt = 0; mt < 2; mt++)
      #pragma unroll
      for (int nt = 0; nt < 4; nt++) sc[mt][nt] = zero4;
    #pragma unroll
    for (int nt = 0; nt < 4; ++nt) {
      int key = nt * 16 + r16;
      #pragma unroll
      for (int ks = 0; ks < 2; ++ks) {
        bf16x8 bk = *(const bf16x8*)(KsB + key * 128 + (((ks * 4 + rg) ^ (key & 7)) << 4));
        sc[0][nt] = __builtin_amdgcn_mfma_f32_16x16x32_bf16(bk, aq[0][0 + ks], sc[0][nt], 0, 0, 0);
        sc[1][nt] = __builtin_amdgcn_mfma_f32_16x16x32_bf16(bk, aq[1][0 + ks], sc[1][nt], 0, 0, 0);
      }
    }

    // online softmax per m-tile (all in registers; q is lane-local)
    #pragma unroll
    for (int mt = 0; mt < 2; ++mt) {
      const int rowmin = q0 + w * 32 + mt * 16;
      if (kt * 64 + 63 > rowmin) {           // causal mask needed
        const int qg = rowmin + r16;
        #pragma unroll
        for (int nt = 0; nt < 4; nt++) {
          int kg = kt * 64 + nt * 16 + rg * 4;
          #pragma unroll
          for (int r = 0; r < 4; r++)
            sc[mt][nt][r] = (kg + r > qg) ? -1e30f : sc[mt][nt][r];
        }
      }
      float pm = -3e38f;
      #pragma unroll
      for (int nt = 0; nt < 4; nt++)
        #pragma unroll
        for (int r = 0; r < 4; r++) pm = fmaxf(pm, sc[mt][nt][r]);
      pm = fmaxf(pm, __shfl_xor(pm, 16, 64));
      pm = fmaxf(pm, __shfl_xor(pm, 32, 64));

      if (!__all(pm <= mrow[mt] + 8.0f)) {   // defer-max: rescale only on growth
        float newm = fmaxf(mrow[mt], pm);
        float scl = exp2f(mrow[mt] - newm);
        mrow[mt] = newm;
        acc_l[mt][0] *= scl;
        #pragma unroll
        for (int nt = 0; nt < 4; nt++) {
          acc_o[mt][nt][0] *= scl; acc_o[mt][nt][1] *= scl;
          acc_o[mt][nt][2] *= scl; acc_o[mt][nt][3] *= scl;
        }
      }
      // exp2 + pack to bf16 + stage P (wave-private, in-order DS)
      #pragma unroll
      for (int nt = 0; nt < 4; nt++) {
        float p0 = exp2f(sc[mt][nt][0] - mrow[mt]);
        float p1 = exp2f(sc[mt][nt][1] - mrow[mt]);
        float p2 = exp2f(sc[mt][nt][2] - mrow[mt]);
        float p3 = exp2f(sc[mt][nt][3] - mrow[mt]);
        i32x2 pk2 = { cvtpk(p0, p1), cvtpk(p2, p3) };
        *(i32x2*)(Pw + mt * 2304 + r16 * 144 + nt * 32 + rg * 8) = pk2;
      }
    }

    // O^T += V^T P^T ; l += 1.P^T   (A = Vt rows d, B = P cols q)
    #pragma unroll
    for (int ks = 0; ks < 2; ++ks) {
      bf16x8 pb0 = *(const bf16x8*)(Pw +        r16 * 144 + ks * 64 + rg * 16);
      bf16x8 pb1 = *(const bf16x8*)(Pw + 2304 + r16 * 144 + ks * 64 + rg * 16);
      acc_l[0] = __builtin_amdgcn_mfma_f32_16x16x32_bf16(ones, pb0, acc_l[0], 0, 0, 0);
      acc_l[1] = __builtin_amdgcn_mfma_f32_16x16x32_bf16(ones, pb1, acc_l[1], 0, 0, 0);
      #pragma unroll
      for (int nt = 0; nt < 4; ++nt) {
        int d = nt * 16 + r16;
        bf16x8 av = *(const bf16x8*)(VtB + d * 128 + (((ks * 4 + rg) ^ (d & 7)) << 4));
        acc_o[0][nt] = __builtin_amdgcn_mfma_f32_16x16x32_bf16(av, pb0, acc_o[0][nt], 0, 0, 0);
        acc_o[1][nt] = __builtin_amdgcn_mfma_f32_16x16x32_bf16(av, pb1, acc_o[1][nt], 0, 0, 0);
      }
    }
  }

  // epilogue: normalize by l (per-lane: col q = r16), write bf16x4 per (mt,nt)
  #pragma unroll
  for (int mt = 0; mt < 2; mt++) {
    float inv = 1.0f / acc_l[mt][0];
    int qg = q0 + w * 32 + mt * 16 + r16;
    short* op = attnb + (size_t)qg * NQ + h * HDim + rg * 4;
    #pragma unroll
    for (int nt = 0; nt < 4; nt++) {
      bf16x4 pk;
      pk[0] = f2bf(acc_o[mt][nt][0] * inv);
      pk[1] = f2bf(acc_o[mt][nt][1] * inv);
      pk[2] = f2bf(acc_o[mt][nt][2] * inv);
      pk[3] = f2bf(acc_o[mt][nt][3] * inv);
      *(bf16x4*)(op + nt * 16) = pk;
    }
  }
}

// ---------------------------------------------------------------------------
extern "C" void kernel_launch(void* const* d_in, const int* in_sizes, int n_in,
                              void* d_out, int out_size, void* d_ws, size_t ws_size,
                              hipStream_t stream)
{
  const float* hs = (const float*)d_in[0];
  // d_in[1] = attention_mask (exactly causal; handled analytically)
  const float* Wq = (const float*)d_in[2];
  const float* bq = (const float*)d_in[3];
  const float* Wk = (const float*)d_in[4];
  const float* bk = (const float*)d_in[5];
  const float* Wv = (const float*)d_in[6];
  const float* bv = (const float*)d_in[7];
  const float* Wo = (const float*)d_in[8];

  short* hsb  = (short*)d_ws;                     // [4096][896]  bf16
  short* wtq  = hsb + (size_t)S_ * Dm;            // [1152][896]  bf16
  short* wto  = wtq + (size_t)1152 * 896;         // [896][896]   bf16
  float* cost = (float*)(wto + (size_t)896 * 896);// [4096][32]   f32
  float* sint = cost + (size_t)S_ * 32;           // [4096][32]   f32
  short* qkb  = (short*)(sint + (size_t)S_ * 32); // [4096][1024] bf16
  short* vtb  = qkb + (size_t)S_ * NQK;           // [128][4096]  bf16 (V^T)
  short* attnb= vtb + (size_t)NK * S_;            // [4096][896]  bf16
  float* out  = (float*)d_out;

  hipLaunchKernelGGL(prep_small, dim3(2304), dim3(256), 0, stream, hs, hsb, cost, sint);
  hipLaunchKernelGGL(transpose_all, dim3(14, 32), dim3(256), 0, stream,
                     Wq, Wk, Wv, Wo, wtq, wto);
  hipLaunchKernelGGL((gemm128<0>), dim3(32, 9), dim3(256), 0, stream,
                     hsb, wtq, bq, bk, bv, cost, sint, qkb, vtb, (float*)nullptr);
  hipLaunchKernelGGL(flash_mfma, dim3(32, NHd), dim3(256), 0, stream,
                     qkb, vtb, attnb);
  hipLaunchKernelGGL((gemm128<1>), dim3(32, 7), dim3(256), 0, stream,
                     attnb, wto, bq, bk, bv, cost, sint,
                     (short*)nullptr, (short*)nullptr, out);
}

// Round 6
// 160.819 us; speedup vs baseline: 1.2167x; 1.2167x over previous
//
#include <hip/hip_runtime.h>
#include <math.h>

// Problem constants
constexpr int S_    = 4096;
constexpr int Dm    = 896;
constexpr int NHd   = 14;
constexpr int NKVh  = 2;
constexpr int HDim  = 64;
constexpr int NQ    = NHd * HDim;        // 896
constexpr int NK    = NKVh * HDim;       // 128
constexpr int NQK   = NQ + NK;           // 1024 (qk buffer row stride)
constexpr int GROUPS = NHd / NKVh;       // 7
constexpr float L2B   = 19.9315685693241740873f;  // log2(1e6)
constexpr float LOG2E = 1.44269504088896340736f;

typedef __attribute__((ext_vector_type(8))) short bf16x8;
typedef __attribute__((ext_vector_type(4))) short bf16x4;
typedef __attribute__((ext_vector_type(4))) float f32x4;
typedef __attribute__((ext_vector_type(2))) int   i32x2;

__device__ __forceinline__ short f2bf(float f) {   // RNE float->bf16
  unsigned u = __builtin_bit_cast(unsigned, f);
  unsigned r = (u + 0x7FFFu + ((u >> 16) & 1u)) >> 16;
  return (short)r;
}
__device__ __forceinline__ float bf2f(short s) {
  return __builtin_bit_cast(float, ((unsigned)(unsigned short)s) << 16);
}

__device__ __forceinline__ int cvtpk(float lo, float hi) {  // 2xf32 -> packed bf16
  int r;
  asm("v_cvt_pk_bf16_f32 %0, %1, %2" : "=v"(r) : "v"(lo), "v"(hi));
  return r;
}

// async global->LDS, 16 bytes per lane; lds dest must be wave-uniform (HW adds lane*16)
__device__ __forceinline__ void gload16(const void* g, void* l) {
  __builtin_amdgcn_global_load_lds(
      (const __attribute__((address_space(1))) unsigned int*)g,
      (__attribute__((address_space(3))) unsigned int*)l, 16, 0, 0);
}

// ---------------------------------------------------------------------------
// Prep A: cvt hidden_states f32->bf16 (blocks 0..1791) + RoPE tables (1792..2303)
// ---------------------------------------------------------------------------
__global__ __launch_bounds__(256) void prep_small(
    const float* __restrict__ hs, short* __restrict__ hsb,
    float* __restrict__ cost, float* __restrict__ sint)
{
  int bid = blockIdx.x;
  if (bid < 1792) {
    int idx = bid * 256 + threadIdx.x;
    float4 a = ((const float4*)hs)[idx * 2];
    float4 b = ((const float4*)hs)[idx * 2 + 1];
    bf16x8 o;
    o[0] = f2bf(a.x); o[1] = f2bf(a.y); o[2] = f2bf(a.z); o[3] = f2bf(a.w);
    o[4] = f2bf(b.x); o[5] = f2bf(b.y); o[6] = f2bf(b.z); o[7] = f2bf(b.w);
    ((bf16x8*)hsb)[idx] = o;
  } else {
    int idx = (bid - 1792) * 256 + threadIdx.x;   // m*32 + j
    int m = idx >> 5, j = idx & 31;
    float invf = exp2f(-(float)j * (L2B / 32.0f));
    float th = (float)m * invf;
    float s, c;
    sincosf(th, &s, &c);
    cost[idx] = c;
    sint[idx] = s;
  }
}

// ---------------------------------------------------------------------------
// Prep B: transpose all weights f32 -> bf16.  grid (14, 32)
// ---------------------------------------------------------------------------
__global__ __launch_bounds__(256) void transpose_all(
    const float* __restrict__ Wq, const float* __restrict__ Wk,
    const float* __restrict__ Wv, const float* __restrict__ Wo,
    short* __restrict__ wtq, short* __restrict__ wto)
{
  __shared__ float t[64 * 68];
  const int kt = blockIdx.x;
  const int by = blockIdx.y;
  const int tid = threadIdx.x;

  const float* src; int srcN, nt; short* dst; int rowOff;
  if (by < 14)      { src = Wq; srcN = NQ; nt = by;      dst = wtq; rowOff = 0; }
  else if (by < 16) { src = Wk; srcN = NK; nt = by - 14; dst = wtq; rowOff = 896; }
  else if (by < 18) { src = Wv; srcN = NK; nt = by - 16; dst = wtq; rowOff = 1024; }
  else              { src = Wo; srcN = NQ; nt = by - 18; dst = wto; rowOff = 0; }

  #pragma unroll
  for (int i = 0; i < 4; i++) {
    int idx = tid + i * 256;
    int r = idx >> 4, c4 = (idx & 15) * 4;
    *(float4*)&t[r * 68 + c4] =
        *(const float4*)&src[(size_t)(kt * 64 + r) * srcN + nt * 64 + c4];
  }
  __syncthreads();
  const int nl = tid >> 2;
  const int kc = (tid & 3) * 16;
  bf16x8 o0, o1;
  #pragma unroll
  for (int i = 0; i < 8; i++) o0[i] = f2bf(t[(kc + i) * 68 + nl]);
  #pragma unroll
  for (int i = 0; i < 8; i++) o1[i] = f2bf(t[(kc + 8 + i) * 68 + nl]);
  short* dp = dst + (size_t)(rowOff + nt * 64 + nl) * 896 + kt * 64 + kc;
  *(bf16x8*)dp = o0;
  *(bf16x8*)(dp + 8) = o1;
}

// ---------------------------------------------------------------------------
// MFMA GEMM, 128x128 tile, BK=64, 4 waves (2x2), m97 structure.
// EPI==0: QKV epilogue (bias + RoPE; Q scaled by log2e/8 for exp2 softmax)
// EPI==1: plain f32 store
// ---------------------------------------------------------------------------
template<int EPI>
__global__ __launch_bounds__(256) void gemm128(
    const short* __restrict__ A, const short* __restrict__ Bt,
    const float* __restrict__ biasq, const float* __restrict__ biask,
    const float* __restrict__ biasv,
    const float* __restrict__ cost, const float* __restrict__ sint,
    short* __restrict__ qkb, short* __restrict__ vtb,
    float* __restrict__ outp)
{
  __shared__ short Als[128 * 64];
  __shared__ short Bls[128 * 64];
  const int tid = threadIdx.x;
  const int lane = tid & 63;
  const int w = tid >> 6;
  const int wm = w >> 1, wn = w & 1;
  const int r16 = lane & 15, rg = lane >> 4;
  const int bm = blockIdx.x, bn = blockIdx.y;

  const f32x4 zero4 = {0.f, 0.f, 0.f, 0.f};
  f32x4 acc[4][4];
  #pragma unroll
  for (int mt = 0; mt < 4; mt++)
    #pragma unroll
    for (int nt = 0; nt < 4; nt++) acc[mt][nt] = zero4;

  const int srow = (lane >> 3);
  const int scol = (lane & 7) * 8;

  for (int kt = 0; kt < 14; ++kt) {
    __syncthreads();
    #pragma unroll
    for (int i = 0; i < 4; i++) {
      int c = i * 4 + w;
      int row = c * 8 + srow;
      gload16(A  + (size_t)(bm * 128 + row) * 896 + kt * 64 + scol, &Als[c * 512]);
      gload16(Bt + (size_t)(bn * 128 + row) * 896 + kt * 64 + scol, &Bls[c * 512]);
    }
    __syncthreads();

    bf16x8 af[4][2], bfr[4][2];
    #pragma unroll
    for (int mt = 0; mt < 4; mt++)
      #pragma unroll
      for (int ks = 0; ks < 2; ks++)
        af[mt][ks] = *(const bf16x8*)&Als[(wm * 64 + mt * 16 + r16) * 64 + ks * 32 + rg * 8];
    #pragma unroll
    for (int nt = 0; nt < 4; nt++)
      #pragma unroll
      for (int ks = 0; ks < 2; ks++)
        bfr[nt][ks] = *(const bf16x8*)&Bls[(wn * 64 + nt * 16 + r16) * 64 + ks * 32 + rg * 8];
    #pragma unroll
    for (int mt = 0; mt < 4; mt++)
      #pragma unroll
      for (int nt = 0; nt < 4; nt++)
        #pragma unroll
        for (int ks = 0; ks < 2; ks++)
          acc[mt][nt] = __builtin_amdgcn_mfma_f32_16x16x32_bf16(
              af[mt][ks], bfr[nt][ks], acc[mt][nt], 0, 0, 0);
  }

  if (EPI == 0) {
    const int nbase = bn * 128 + wn * 64;
    if (bn < 8) {
      const float scl = (bn < 7) ? (0.125f * LOG2E) : 1.0f;
      const float* bias = (bn < 7) ? biasq : (biask - 896);
      #pragma unroll
      for (int mt = 0; mt < 4; mt++) {
        const int m0 = bm * 128 + wm * 64 + mt * 16 + rg * 4;
        #pragma unroll
        for (int nt = 0; nt < 4; nt++) {
          int n = nbase + nt * 16 + r16;
          int j = n & 31;
          float sgn = (n & 32) ? 1.f : -1.f;
          float b0 = bias[n], b1 = bias[n ^ 32];
          #pragma unroll
          for (int r = 0; r < 4; r++) {
            int m = m0 + r;
            float c_ = cost[m * 32 + j], s_ = sint[m * 32 + j];
            float val = ((acc[mt][nt][r] + b0) * c_ +
                         sgn * (acc[mt][nt ^ 2][r] + b1) * s_) * scl;
            qkb[(size_t)m * NQK + n] = f2bf(val);
          }
        }
      }
    } else {
      #pragma unroll
      for (int mt = 0; mt < 4; mt++) {
        const int m0 = bm * 128 + wm * 64 + mt * 16 + rg * 4;
        #pragma unroll
        for (int nt = 0; nt < 4; nt++) {
          int vc = wn * 64 + nt * 16 + r16;
          float b0 = biasv[vc];
          bf16x4 pk;
          #pragma unroll
          for (int r = 0; r < 4; r++) pk[r] = f2bf(acc[mt][nt][r] + b0);
          *(bf16x4*)&vtb[(size_t)vc * S_ + m0] = pk;
        }
      }
    }
  } else {
    #pragma unroll
    for (int mt = 0; mt < 4; mt++) {
      const int m0 = bm * 128 + wm * 64 + mt * 16 + rg * 4;
      #pragma unroll
      for (int nt = 0; nt < 4; nt++) {
        int n = bn * 128 + wn * 64 + nt * 16 + r16;
        #pragma unroll
        for (int r = 0; r < 4; r++)
          outp[(size_t)(m0 + r) * NQ + n] = acc[mt][nt][r];
      }
    }
  }
}

// ---------------------------------------------------------------------------
// Flash attention v5: swapped QK^T, QBLK=128, KBLK=64, 4 waves x 32 q-rows.
// Balanced flash-decoding grid: 672 blocks = 14 heads x 48 units:
//   e<32 : half s=e&1 of q-tile qt=31-(e>>1) (qt>=16), chunks [s(qt+1),(s+1)(qt+1))
//          -> writes UNNORMALIZED partial O (bf16) + (m,l) f32 records
//   e>=32: whole q-tile qt=47-e (qt<16) -> writes final attnb
// Double-buffered K/V via global_load_lds; one barrier + one (hidden) vmcnt(0)
// per iteration; prefetch issued right after the barrier.
// ---------------------------------------------------------------------------
__global__ __launch_bounds__(256, 4) void flash_mfma(
    const short* __restrict__ qkb, const short* __restrict__ vtb,
    short* __restrict__ attnb, short* __restrict__ orec,
    float* __restrict__ mlrec)
{
  __shared__ __align__(16) char lds[51200];   // 2 x (K 8K | V 8K) | P 4x4608

  const int tid  = threadIdx.x;
  const int lane = tid & 63;
  const int w    = tid >> 6;          // m-group: rows w*32
  const int r16  = lane & 15;         // q within 16-tile
  const int rg   = lane >> 4;
  const int bid  = blockIdx.x;
  const int h    = bid % 14;
  const int e    = bid / 14;

  int qt, kt_lo, kt_hi, recid;
  if (e < 32) {
    qt = 31 - (e >> 1);
    int s = e & 1;
    kt_lo = s * (qt + 1);
    kt_hi = kt_lo + (qt + 1);
    recid = (h * 16 + (qt - 16)) * 2 + s;
  } else {
    qt = 47 - e;
    kt_lo = 0;
    kt_hi = 2 * qt + 2;
    recid = -1;
  }
  const int kv = h / GROUPS;
  const int q0 = qt * 128;
  char* Pw = lds + 32768 + w * 4608;  // per-wave P: [2 mt][16 q][144 B]
  const int kbase2 = (NQ + kv * HDim) * 2;

  // staging sources (pre-swizzled global chunk so LDS stays linear)
  const char* qkbB = (const char*)qkb;
  const char* vtbB = (const char*)vtb;
  const int c8   = tid & 7;
  const int key0 = tid >> 3;          // 0..31 (K row / V hd row)
  const int key1 = key0 + 32;
  const char* ksrc0 = qkbB + (size_t)(kt_lo * 64 + key0) * 2048 + kbase2 + ((c8 ^ (key0 & 7)) << 4);
  const char* ksrc1 = qkbB + (size_t)(kt_lo * 64 + key1) * 2048 + kbase2 + ((c8 ^ (key1 & 7)) << 4);
  const char* vsrc0 = vtbB + (size_t)(kv * 64 + key0) * 8192 + (size_t)kt_lo * 128 + ((c8 ^ (key0 & 7)) << 4);
  const char* vsrc1 = vtbB + (size_t)(kv * 64 + key1) * 8192 + (size_t)kt_lo * 128 + ((c8 ^ (key1 & 7)) << 4);

  // Q fragments (already scaled by log2e/8): B-operand, col = q = r16
  bf16x8 aq[2][2];
  #pragma unroll
  for (int mt = 0; mt < 2; ++mt) {
    const short* qp = qkb + (size_t)(q0 + w * 32 + mt * 16 + r16) * NQK + h * HDim + rg * 8;
    aq[mt][0] = *(const bf16x8*)qp;
    aq[mt][1] = *(const bf16x8*)(qp + 32);
  }

  const f32x4 zero4 = {0.f, 0.f, 0.f, 0.f};
  f32x4 acc_o[2][4];                 // D[d][q]: d-tile nt, col q = r16
  f32x4 acc_l[2];                    // rowsum via ones-MFMA (use [0])
  float mrow[2] = {0.f, 0.f};        // deferred running max (exp2 domain)
  #pragma unroll
  for (int mt = 0; mt < 2; mt++) {
    acc_l[mt] = zero4;
    #pragma unroll
    for (int nt = 0; nt < 4; nt++) acc_o[mt][nt] = zero4;
  }

  bf16x8 ones;
  #pragma unroll
  for (int j = 0; j < 8; j++) ones[j] = (short)0x3F80;  // bf16(1.0)

  // prologue: issue first tile into buffer 0
  {
    char* Kb = lds;
    char* Vb = lds + 8192;
    gload16(ksrc0, Kb + w * 1024);
    gload16(ksrc1, Kb + 4096 + w * 1024);
    gload16(vsrc0, Vb + w * 1024);
    gload16(vsrc1, Vb + 4096 + w * 1024);
    ksrc0 += 131072; ksrc1 += 131072;
    vsrc0 += 128;    vsrc1 += 128;
  }

  for (int kt = kt_lo; kt < kt_hi; ++kt) {
    const int cur = (kt - kt_lo) & 1;
    asm volatile("s_waitcnt vmcnt(0)" ::: "memory");  // cur tile landed
    __builtin_amdgcn_s_barrier();                     // all waves done with buf cur^1
    if (kt + 1 < kt_hi) {                             // prefetch next into cur^1
      char* Kb = lds + ((cur ^ 1) << 14);
      char* Vb = Kb + 8192;
      gload16(ksrc0, Kb + w * 1024);
      gload16(ksrc1, Kb + 4096 + w * 1024);
      gload16(vsrc0, Vb + w * 1024);
      gload16(vsrc1, Vb + 4096 + w * 1024);
      ksrc0 += 131072; ksrc1 += 131072;
      vsrc0 += 128;    vsrc1 += 128;
    }
    __builtin_amdgcn_sched_barrier(0);
    const char* KsB = lds + (cur << 14);
    const char* VtB = KsB + 8192;

    // S^T = K Q^T : sc[mt][nt] -> D[key = nt*16 + rg*4 + r][q = r16]
    f32x4 sc[2][4];
    #pragma unroll
    for (int mt = 0; mt < 2; mt++)
      #pragma unroll
      for (int nt = 0; nt < 4; nt++) sc[mt][nt] = zero4;
    #pragma unroll
    for (int nt = 0; nt < 4; ++nt) {
      int key = nt * 16 + r16;
      #pragma unroll
      for (int ks = 0; ks < 2; ++ks) {
        bf16x8 bk = *(const bf16x8*)(KsB + key * 128 + (((ks * 4 + rg) ^ (key & 7)) << 4));
        sc[0][nt] = __builtin_amdgcn_mfma_f32_16x16x32_bf16(bk, aq[0][ks], sc[0][nt], 0, 0, 0);
        sc[1][nt] = __builtin_amdgcn_mfma_f32_16x16x32_bf16(bk, aq[1][ks], sc[1][nt], 0, 0, 0);
      }
    }

    // online softmax per m-tile (all in registers; q is lane-local)
    #pragma unroll
    for (int mt = 0; mt < 2; ++mt) {
      const int rowmin = q0 + w * 32 + mt * 16;
      if (kt * 64 + 63 > rowmin) {           // causal mask needed
        const int qg = rowmin + r16;
        #pragma unroll
        for (int nt = 0; nt < 4; nt++) {
          int kg = kt * 64 + nt * 16 + rg * 4;
          #pragma unroll
          for (int r = 0; r < 4; r++)
            sc[mt][nt][r] = (kg + r > qg) ? -1e30f : sc[mt][nt][r];
        }
      }
      float pm = -3e38f;
      #pragma unroll
      for (int nt = 0; nt < 4; nt++)
        #pragma unroll
        for (int r = 0; r < 4; r++) pm = fmaxf(pm, sc[mt][nt][r]);
      pm = fmaxf(pm, __shfl_xor(pm, 16, 64));
      pm = fmaxf(pm, __shfl_xor(pm, 32, 64));

      if (!__all(pm <= mrow[mt] + 8.0f)) {   // defer-max: rescale only on growth
        float newm = fmaxf(mrow[mt], pm);
        float scl = exp2f(mrow[mt] - newm);
        mrow[mt] = newm;
        acc_l[mt][0] *= scl;
        #pragma unroll
        for (int nt = 0; nt < 4; nt++) {
          acc_o[mt][nt][0] *= scl; acc_o[mt][nt][1] *= scl;
          acc_o[mt][nt][2] *= scl; acc_o[mt][nt][3] *= scl;
        }
      }
      // exp2 + pack to bf16 + stage P (wave-private, in-order DS)
      #pragma unroll
      for (int nt = 0; nt < 4; nt++) {
        float p0 = exp2f(sc[mt][nt][0] - mrow[mt]);
        float p1 = exp2f(sc[mt][nt][1] - mrow[mt]);
        float p2 = exp2f(sc[mt][nt][2] - mrow[mt]);
        float p3 = exp2f(sc[mt][nt][3] - mrow[mt]);
        i32x2 pk2 = { cvtpk(p0, p1), cvtpk(p2, p3) };
        *(i32x2*)(Pw + mt * 2304 + r16 * 144 + nt * 32 + rg * 8) = pk2;
      }
    }

    // O^T += V^T P^T ; l += 1.P^T
    #pragma unroll
    for (int ks = 0; ks < 2; ++ks) {
      bf16x8 pb0 = *(const bf16x8*)(Pw +        r16 * 144 + ks * 64 + rg * 16);
      bf16x8 pb1 = *(const bf16x8*)(Pw + 2304 + r16 * 144 + ks * 64 + rg * 16);
      acc_l[0] = __builtin_amdgcn_mfma_f32_16x16x32_bf16(ones, pb0, acc_l[0], 0, 0, 0);
      acc_l[1] = __builtin_amdgcn_mfma_f32_16x16x32_bf16(ones, pb1, acc_l[1], 0, 0, 0);
      #pragma unroll
      for (int nt = 0; nt < 4; ++nt) {
        int d = nt * 16 + r16;
        bf16x8 av = *(const bf16x8*)(VtB + d * 128 + (((ks * 4 + rg) ^ (d & 7)) << 4));
        acc_o[0][nt] = __builtin_amdgcn_mfma_f32_16x16x32_bf16(av, pb0, acc_o[0][nt], 0, 0, 0);
        acc_o[1][nt] = __builtin_amdgcn_mfma_f32_16x16x32_bf16(av, pb1, acc_o[1][nt], 0, 0, 0);
      }
    }
  }

  if (recid < 0) {
    // whole tile: normalize by l and write bf16 attnb
    #pragma unroll
    for (int mt = 0; mt < 2; mt++) {
      float inv = 1.0f / acc_l[mt][0];
      int qg = q0 + w * 32 + mt * 16 + r16;
      short* op = attnb + (size_t)qg * NQ + h * HDim + rg * 4;
      #pragma unroll
      for (int nt = 0; nt < 4; nt++) {
        bf16x4 pk;
        pk[0] = f2bf(acc_o[mt][nt][0] * inv);
        pk[1] = f2bf(acc_o[mt][nt][1] * inv);
        pk[2] = f2bf(acc_o[mt][nt][2] * inv);
        pk[3] = f2bf(acc_o[mt][nt][3] * inv);
        *(bf16x4*)(op + nt * 16) = pk;
      }
    }
  } else {
    // split half: write UNNORMALIZED O record [128 q][64 d] bf16 + (m,l) f32
    short* orp = orec + (size_t)recid * 8192;
    #pragma unroll
    for (int mt = 0; mt < 2; mt++) {
      int qloc = w * 32 + mt * 16 + r16;
      #pragma unroll
      for (int nt = 0; nt < 4; nt++) {
        bf16x4 pk;
        pk[0] = f2bf(acc_o[mt][nt][0]);
        pk[1] = f2bf(acc_o[mt][nt][1]);
        pk[2] = f2bf(acc_o[mt][nt][2]);
        pk[3] = f2bf(acc_o[mt][nt][3]);
        *(bf16x4*)(orp + qloc * 64 + nt * 16 + rg * 4) = pk;
      }
      if (rg == 0) {
        float2 ml = {mrow[mt], acc_l[mt][0]};
        *(float2*)(mlrec + ((size_t)recid * 128 + qloc) * 2) = ml;
      }
    }
  }
}

// ---------------------------------------------------------------------------
// Merge the two key-half partials for qt>=16 units -> bf16 attnb.
// grid 224 (= 14 heads x 16 tiles), 256 threads (2 per q-row).
// ---------------------------------------------------------------------------
__global__ __launch_bounds__(256) void merge_halves(
    const short* __restrict__ orec, const float* __restrict__ mlrec,
    short* __restrict__ attnb)
{
  const int u = blockIdx.x;          // h*16 + (qt-16)
  const int h = u >> 4;
  const int qt = 16 + (u & 15);
  const int tid = threadIdx.x;
  const int qloc = tid >> 1;
  const int d0 = (tid & 1) * 32;

  float2 ml1 = *(const float2*)(mlrec + ((size_t)(u * 2 + 0) * 128 + qloc) * 2);
  float2 ml2 = *(const float2*)(mlrec + ((size_t)(u * 2 + 1) * 128 + qloc) * 2);
  float M  = fmaxf(ml1.x, ml2.x);
  float a1 = exp2f(ml1.x - M), a2 = exp2f(ml2.x - M);
  float inv = 1.0f / (a1 * ml1.y + a2 * ml2.y);
  float s1 = a1 * inv, s2 = a2 * inv;

  const short* O1 = orec + (size_t)(u * 2 + 0) * 8192 + qloc * 64 + d0;
  const short* O2 = orec + (size_t)(u * 2 + 1) * 8192 + qloc * 64 + d0;
  short* op = attnb + (size_t)(qt * 128 + qloc) * NQ + h * HDim + d0;
  #pragma unroll
  for (int i = 0; i < 4; i++) {
    bf16x8 x1 = *(const bf16x8*)(O1 + i * 8);
    bf16x8 x2 = *(const bf16x8*)(O2 + i * 8);
    bf16x8 o;
    #pragma unroll
    for (int j = 0; j < 8; j++)
      o[j] = f2bf(s1 * bf2f(x1[j]) + s2 * bf2f(x2[j]));
    *(bf16x8*)(op + i * 8) = o;
  }
}

// ---------------------------------------------------------------------------
extern "C" void kernel_launch(void* const* d_in, const int* in_sizes, int n_in,
                              void* d_out, int out_size, void* d_ws, size_t ws_size,
                              hipStream_t stream)
{
  const float* hs = (const float*)d_in[0];
  // d_in[1] = attention_mask (exactly causal; handled analytically)
  const float* Wq = (const float*)d_in[2];
  const float* bq = (const float*)d_in[3];
  const float* Wk = (const float*)d_in[4];
  const float* bk = (const float*)d_in[5];
  const float* Wv = (const float*)d_in[6];
  const float* bv = (const float*)d_in[7];
  const float* Wo = (const float*)d_in[8];

  short* hsb  = (short*)d_ws;                     // [4096][896]  bf16
  short* wtq  = hsb + (size_t)S_ * Dm;            // [1152][896]  bf16
  short* wto  = wtq + (size_t)1152 * 896;         // [896][896]   bf16
  float* cost = (float*)(wto + (size_t)896 * 896);// [4096][32]   f32
  float* sint = cost + (size_t)S_ * 32;           // [4096][32]   f32
  short* qkb  = (short*)(sint + (size_t)S_ * 32); // [4096][1024] bf16
  short* vtb  = qkb + (size_t)S_ * NQK;           // [128][4096]  bf16 (V^T)
  short* attnb= vtb + (size_t)NK * S_;            // [4096][896]  bf16
  float* out  = (float*)d_out;

  // partial records reuse regions dead after gemm<0>:
  short* orec  = hsb;            // 448 x 8192 bf16 = exactly hsb's size
  float* mlrec = (float*)wtq;    // 448 x 128 x 2 f32 = 459 KB < wtq size

  hipLaunchKernelGGL(prep_small, dim3(2304), dim3(256), 0, stream, hs, hsb, cost, sint);
  hipLaunchKernelGGL(transpose_all, dim3(14, 32), dim3(256), 0, stream,
                     Wq, Wk, Wv, Wo, wtq, wto);
  hipLaunchKernelGGL((gemm128<0>), dim3(32, 9), dim3(256), 0, stream,
                     hsb, wtq, bq, bk, bv, cost, sint, qkb, vtb, (float*)nullptr);
  hipLaunchKernelGGL(flash_mfma, dim3(672), dim3(256), 0, stream,
                     qkb, vtb, attnb, orec, mlrec);
  hipLaunchKernelGGL(merge_halves, dim3(224), dim3(256), 0, stream,
                     orec, mlrec, attnb);
  hipLaunchKernelGGL((gemm128<1>), dim3(32, 7), dim3(256), 0, stream,
                     attnb, wto, bq, bk, bv, cost, sint,
                     (short*)nullptr, (short*)nullptr, out);
}